// Round 7
// baseline (60.327 us; speedup 1.0000x reference)
//
#include <hip/hip_runtime.h>

#define B_ 64
#define S_ 200
#define H_ 256
#define A_ 16
#define M_ (B_*S_)
#define NEGV (-1000000000.0f)

typedef unsigned short ushortT;
typedef __attribute__((ext_vector_type(8))) short short8;
typedef __attribute__((ext_vector_type(4))) float f32x4;

__device__ __forceinline__ ushortT bf16u(float f) {
  unsigned int u = __builtin_bit_cast(unsigned int, f);
  unsigned int r = (u + 0x7fffu + ((u >> 16) & 1u)) >> 16;
  return (ushortT)r;
}
__device__ __forceinline__ float bf2f(ushortT u) {
  unsigned int v = ((unsigned int)u) << 16;
  return __builtin_bit_cast(float, v);
}

// ---------------- prepT: weight transposes only (32 blocks) ----------------
__global__ __launch_bounds__(256) void prepT_kernel(
    const float* __restrict__ Wa1, const float* __restrict__ W_lin,
    ushortT* __restrict__ Wa1T, ushortT* __restrict__ WlinT)
{
  __shared__ float T[64*65];
  const int blk = blockIdx.x, t = threadIdx.x;
  int wsel = blk >> 4;
  int tile = blk & 15;
  const float* W = wsel ? W_lin : Wa1;
  ushortT* WT = wsel ? WlinT : Wa1T;
  int tr = (tile >> 2) * 64, tc = (tile & 3) * 64;
  #pragma unroll
  for (int p = 0; p < 16; ++p) {
    int r = p*4 + (t >> 6);
    int c = t & 63;
    T[c*65 + r] = W[(tr + r)*H_ + tc + c];
  }
  __syncthreads();
  #pragma unroll
  for (int p = 0; p < 16; ++p) {
    int n = p*4 + (t >> 6);
    int k = t & 63;
    WT[(tc + n)*H_ + tr + k] = bf16u(T[n*65 + k]);
  }
}

// ---------------- gemmx: 600 blocks x 512 thr ----------------
// blocks 0..199: fused dual MFMA GEMM (B dbuf, 1 barrier/k-step).
// blocks 200..599: gates f32 (32 rows each) + softmax + argmax idx.
#define ASTR 264
__global__ __launch_bounds__(512) void gemmx_kernel(
    const float* __restrict__ item, const int* __restrict__ iseq,
    const int* __restrict__ tseq, const float* __restrict__ pos,
    const float* __restrict__ tdt, const float* __restrict__ tdn,
    const float* __restrict__ asp,
    const ushortT* __restrict__ Wa1T, const ushortT* __restrict__ WlinT,
    const float* __restrict__ ba1, const float* __restrict__ Wa2,
    const float* __restrict__ ba2, const float* __restrict__ b_lin,
    const float* __restrict__ g_ln, const float* __restrict__ b_ln,
    float* __restrict__ w_out, ushortT* __restrict__ moe_outB,
    float* __restrict__ graw, float* __restrict__ gates_sm,
    float* __restrict__ idxf)
{
  // 16896 u16 Atma | 16896 u16 Aitm | 4x10240 u16 B (weight,buf)  = 149504 B
  __shared__ __align__(16) ushortT smem[74752];
  __shared__ int sL[64], ttL[64], tnL[64];
  __shared__ float wp[2][64], ln1[2][64], ln2[2][64], mus[64], rss[64];

  const int t = threadIdx.x;

  if (blockIdx.x >= 200) {
    // ================= gates role =================
    float* aspl = (float*)smem;          // 16x260 f32
    float* gLs  = aspl + 16*260;         // 32x20 f32
    const int m0 = (blockIdx.x - 200) * 32;
    #pragma unroll
    for (int i = 0; i < 2; ++i) {
      int e = t + 512*i;
      int r = e >> 6, c = e & 63;
      *(float4*)&aspl[r*260 + 4*c] = *(const float4*)&asp[r*H_ + 4*c];
    }
    __syncthreads();
    const int r = t >> 4, a = t & 15;
    const int m = m0 + r;
    float g = 0.f;
    #pragma unroll 8
    for (int k4 = 0; k4 < 64; ++k4) {
      float4 xv = *(const float4*)&item[(size_t)m*H_ + 4*k4];
      float4 av = *(const float4*)&aspl[a*260 + 4*k4];
      g += xv.x*av.x + xv.y*av.y + xv.z*av.z + xv.w*av.w;
    }
    gLs[r*20 + a] = g;
    __syncthreads();
    if (t < 128) {
      int rr = t >> 2, q = t & 3;
      float4 gv;
      gv.x = gLs[rr*20 + 4*q + 0]; gv.y = gLs[rr*20 + 4*q + 1];
      gv.z = gLs[rr*20 + 4*q + 2]; gv.w = gLs[rr*20 + 4*q + 3];
      *(float4*)&graw[(m0+rr)*A_ + 4*q] = gv;
    }
    // softmax over a (16-lane groups)
    {
      float v = g;
      float mx = v;
      #pragma unroll
      for (int mk = 1; mk < 16; mk <<= 1) mx = fmaxf(mx, __shfl_xor(mx, mk));
      float e = expf(v - mx);
      float sm = e;
      #pragma unroll
      for (int mk = 1; mk < 16; mk <<= 1) sm += __shfl_xor(sm, mk);
      gates_sm[(size_t)m*A_ + a] = e / sm;
    }
    if (t < 32) {
      float best = gLs[t*20]; int bi = 0;
      #pragma unroll
      for (int aa = 1; aa < 16; ++aa) {
        float v = gLs[t*20 + aa];
        if (v > best) { best = v; bi = aa; }
      }
      idxf[m0 + t] = (float)bi;
    }
    return;
  }

  // ================= GEMM role =================
  ushortT* Atma = smem;
  ushortT* Aitm = smem + 16896;
  ushortT* Bbuf = smem + 33792;        // (g*2+p)*10240 + n*40 + k

  const int m0 = blockIdx.x * 64;
  const int lane = t & 63, w = t >> 6;
  const int g = w >> 2, wl = w & 3;
  const int wm = wl >> 1, wn = wl & 1;
  const int col = lane & 15;
  const int rg  = lane >> 4;

  if (t < 64) {
    int m = m0 + t;
    sL[t]  = m % S_;
    ttL[t] = tseq[2*m];
    tnL[t] = tseq[2*m+1];
  }
  __syncthreads();

  const int arow = t >> 3;          // 0..63
  const int ac4  = (t & 7) * 4;     // 0..28
  const int nr   = t >> 1;          // 0..255
  const int kh   = (t & 1) * 16;
  const int srow = sL[arow], trow = ttL[arow], nrow = tnL[arow];

  // prefetch k-step 0
  float4 pi = *(const float4*)&item[(size_t)(m0+arow)*H_ + ac4];
  float4 pp = *(const float4*)&pos[srow*H_ + ac4];
  float4 pt = *(const float4*)&tdt[trow*H_ + ac4];
  float4 pn = *(const float4*)&tdn[nrow*H_ + ac4];
  uint4 b0a = *(const uint4*)&Wa1T[(size_t)nr*H_ + kh];
  uint4 b0b = *(const uint4*)&Wa1T[(size_t)nr*H_ + kh + 8];
  uint4 b1a = *(const uint4*)&WlinT[(size_t)nr*H_ + kh];
  uint4 b1b = *(const uint4*)&WlinT[(size_t)nr*H_ + kh + 8];

  f32x4 acc[2][8];
  #pragma unroll
  for (int r = 0; r < 2; ++r)
    #pragma unroll
    for (int q = 0; q < 8; ++q) acc[r][q] = (f32x4){0.f,0.f,0.f,0.f};

  // stage k-step 0 into buf 0
  {
    union { ushortT u[4]; uint2 v; } ci, ct;
    ci.u[0] = bf16u(pi.x); ci.u[1] = bf16u(pi.y);
    ci.u[2] = bf16u(pi.z); ci.u[3] = bf16u(pi.w);
    ct.u[0] = bf16u(pi.x + pp.x + pt.x + pn.x);
    ct.u[1] = bf16u(pi.y + pp.y + pt.y + pn.y);
    ct.u[2] = bf16u(pi.z + pp.z + pt.z + pn.z);
    ct.u[3] = bf16u(pi.w + pp.w + pt.w + pn.w);
    *(uint2*)&Aitm[arow*ASTR + ac4] = ci.v;
    *(uint2*)&Atma[arow*ASTR + ac4] = ct.v;
    *(uint4*)&Bbuf[0*10240 + nr*40 + kh]     = b0a;
    *(uint4*)&Bbuf[0*10240 + nr*40 + kh + 8] = b0b;
    *(uint4*)&Bbuf[2*10240 + nr*40 + kh]     = b1a;
    *(uint4*)&Bbuf[2*10240 + nr*40 + kh + 8] = b1b;
  }
  __syncthreads();

  #pragma unroll
  for (int ks = 0; ks < 8; ++ks) {
    const int k0 = ks*32;
    if (ks < 7) {
      const int k1 = k0 + 32;
      pi = *(const float4*)&item[(size_t)(m0+arow)*H_ + k1 + ac4];
      pp = *(const float4*)&pos[srow*H_ + k1 + ac4];
      pt = *(const float4*)&tdt[trow*H_ + k1 + ac4];
      pn = *(const float4*)&tdn[nrow*H_ + k1 + ac4];
      b0a = *(const uint4*)&Wa1T[(size_t)nr*H_ + k1 + kh];
      b0b = *(const uint4*)&Wa1T[(size_t)nr*H_ + k1 + kh + 8];
      b1a = *(const uint4*)&WlinT[(size_t)nr*H_ + k1 + kh];
      b1b = *(const uint4*)&WlinT[(size_t)nr*H_ + k1 + kh + 8];
    }
    // compute k-step ks
    {
      const ushortT* Ab = g ? Aitm : Atma;
      const ushortT* Bb = Bbuf + (g*2 + (ks & 1))*10240;
      short8 af0 = *(const short8*)&Ab[(wm*32 + col)*ASTR + k0 + rg*8];
      short8 af1 = *(const short8*)&Ab[(wm*32 + 16 + col)*ASTR + k0 + rg*8];
      #pragma unroll
      for (int q = 0; q < 8; ++q) {
        short8 bf = *(const short8*)&Bb[(wn*128 + q*16 + col)*40 + rg*8];
        acc[0][q] = __builtin_amdgcn_mfma_f32_16x16x32_bf16(af0, bf, acc[0][q], 0, 0, 0);
        acc[1][q] = __builtin_amdgcn_mfma_f32_16x16x32_bf16(af1, bf, acc[1][q], 0, 0, 0);
      }
    }
    if (ks < 7) {
      const int k1 = k0 + 32;
      const int p = (ks + 1) & 1;
      union { ushortT u[4]; uint2 v; } ci, ct;
      ci.u[0] = bf16u(pi.x); ci.u[1] = bf16u(pi.y);
      ci.u[2] = bf16u(pi.z); ci.u[3] = bf16u(pi.w);
      ct.u[0] = bf16u(pi.x + pp.x + pt.x + pn.x);
      ct.u[1] = bf16u(pi.y + pp.y + pt.y + pn.y);
      ct.u[2] = bf16u(pi.z + pp.z + pt.z + pn.z);
      ct.u[3] = bf16u(pi.w + pp.w + pt.w + pn.w);
      *(uint2*)&Aitm[arow*ASTR + k1 + ac4] = ci.v;
      *(uint2*)&Atma[arow*ASTR + k1 + ac4] = ct.v;
      *(uint4*)&Bbuf[(0*2+p)*10240 + nr*40 + kh]     = b0a;
      *(uint4*)&Bbuf[(0*2+p)*10240 + nr*40 + kh + 8] = b0b;
      *(uint4*)&Bbuf[(1*2+p)*10240 + nr*40 + kh]     = b1a;
      *(uint4*)&Bbuf[(1*2+p)*10240 + nr*40 + kh + 8] = b1b;
    }
    __syncthreads();
  }

  // ---- epilogue ----
  float glv[8], bbv[8];
  if (g == 0) {
    float bav[8], wav[8];
    #pragma unroll
    for (int q = 0; q < 8; ++q) {
      int n = wn*128 + q*16 + col;
      bav[q] = ba1[n]; wav[q] = Wa2[n];
    }
    #pragma unroll
    for (int r = 0; r < 2; ++r)
      #pragma unroll
      for (int j = 0; j < 4; ++j) {
        float p = 0.f;
        #pragma unroll
        for (int q = 0; q < 8; ++q) {
          float h = acc[r][q][j] + bav[q];
          h = (h >= 0.f) ? h : 0.01f*h;
          p += h * wav[q];
        }
        #pragma unroll
        for (int mk = 1; mk < 16; mk <<= 1) p += __shfl_xor(p, mk);
        if (col == 0) wp[wn][wm*32 + r*16 + rg*4 + j] = p;
      }
  } else {
    float blv[8];
    #pragma unroll
    for (int q = 0; q < 8; ++q) {
      int n = wn*128 + q*16 + col;
      blv[q] = b_lin[n]; glv[q] = g_ln[n]; bbv[q] = b_ln[n];
    }
    #pragma unroll
    for (int r = 0; r < 2; ++r)
      #pragma unroll
      for (int j = 0; j < 4; ++j) {
        int row = wm*32 + r*16 + rg*4 + j;
        float s1 = 0.f, s2 = 0.f;
        #pragma unroll
        for (int q = 0; q < 8; ++q) {
          int n = wn*128 + q*16 + col;
          float vv = tanhf(acc[r][q][j] + blv[q]) + bf2f(Aitm[row*ASTR + n]);
          acc[r][q][j] = vv; s1 += vv; s2 += vv*vv;
        }
        #pragma unroll
        for (int mk = 1; mk < 16; mk <<= 1) {
          s1 += __shfl_xor(s1, mk);
          s2 += __shfl_xor(s2, mk);
        }
        if (col == 0) { ln1[wn][row] = s1; ln2[wn][row] = s2; }
      }
  }
  __syncthreads();
  if (t < 64) {
    int row = t, m = m0 + row;
    w_out[m] = (iseq[m] == 0) ? NEGV : (wp[0][row] + wp[1][row] + ba2[0]);
  } else if (t < 128) {
    int row = t - 64;
    float s1 = ln1[0][row] + ln1[1][row];
    float s2 = ln2[0][row] + ln2[1][row];
    float mu  = s1 * (1.0f/H_);
    float var = s2 * (1.0f/H_) - mu*mu;
    mus[row] = mu;
    rss[row] = 1.0f / sqrtf(fmaxf(var, 0.f) + 1e-12f);
  }
  __syncthreads();
  if (g == 1) {
    #pragma unroll
    for (int r = 0; r < 2; ++r)
      #pragma unroll
      for (int j = 0; j < 4; ++j) {
        int row = wm*32 + r*16 + rg*4 + j;
        int m = m0 + row;
        float mu = mus[row], rs = rss[row];
        #pragma unroll
        for (int q = 0; q < 8; ++q) {
          int n = wn*128 + q*16 + col;
          moe_outB[(size_t)m*H_ + n] = bf16u((acc[r][q][j] - mu)*rs*glv[q] + bbv[q]);
        }
      }
  }
}

// ---------------- Phase C: MFMA routing (one block per batch) ----------------
__device__ __forceinline__ float blk_max(float v, float* red) {
  #pragma unroll
  for (int mk = 32; mk; mk >>= 1) v = fmaxf(v, __shfl_xor(v, mk));
  int t = threadIdx.x;
  if ((t & 63) == 0) red[t >> 6] = v;
  __syncthreads();
  if (t < 64) {
    float x = (t < 16) ? red[t] : -3.0e38f;
    #pragma unroll
    for (int mk = 8; mk; mk >>= 1) x = fmaxf(x, __shfl_xor(x, mk));
    if (t == 0) red[0] = x;
  }
  __syncthreads();
  float r = red[0];
  __syncthreads();
  return r;
}

__device__ __forceinline__ float blk_sum(float v, float* red) {
  #pragma unroll
  for (int mk = 32; mk; mk >>= 1) v += __shfl_xor(v, mk);
  int t = threadIdx.x;
  if ((t & 63) == 0) red[t >> 6] = v;
  __syncthreads();
  if (t < 64) {
    float x = (t < 16) ? red[t] : 0.f;
    #pragma unroll
    for (int mk = 8; mk; mk >>= 1) x += __shfl_xor(x, mk);
    if (t == 0) red[0] = x;
  }
  __syncthreads();
  float r = red[0];
  __syncthreads();
  return r;
}

// moeTr layout: [ht=16][ks=7][bp=8][sr=4][hc=16] bf16 (see r4 notes).
#define WGSTR 232
#define CBSTR 260
#define CLSTR 252

__global__ __launch_bounds__(1024) void phaseC_kernel(
    const int* __restrict__ iseq, const float* __restrict__ w_in,
    const ushortT* __restrict__ moeB, const float* __restrict__ idxf,
    const float* __restrict__ graw,
    float* __restrict__ cap_out,    // OUT0
    float* __restrict__ mask_out,   // OUT2
    float* __restrict__ aidx_out)   // OUT4
{
  __shared__ ushortT moeTr[57344];
  __shared__ ushortT wgtT[16*WGSTR];
  __shared__ ushortT capB[16*CBSTR];
  __shared__ float bij[4032];
  __shared__ float n2p[16*17];
  __shared__ float n2s[16];
  __shared__ float tmaL[S_];
  __shared__ float red[16];
  __shared__ float maskf[A_];
  __shared__ int counts[A_], maxpos[A_];
  __shared__ int idxl[S_];
  __shared__ int padl[S_];

  const int t = threadIdx.x;
  const int b = blockIdx.x;
  const int base = b * S_;
  const int lane = t & 63, w = t >> 6;
  const int la = lane & 15, lg = lane >> 4;

  #pragma unroll
  for (int u = 0; u < 4; ++u) {
    int e = t + 1024*u;
    if (e < 3584) {
      int ht = e & 15, s = e >> 4;
      int ks = s >> 5, s4l = (s >> 2) & 7, sr = s & 3;
      int bp = (s4l & 1) ? 4 + (s4l >> 1) : (s4l >> 1);
      int li = ((ht*7 + ks)*8 + bp)*64 + sr*16;
      if (s < S_) {
        const ushortT* gp = &moeB[((size_t)(base + s))*H_ + ht*16];
        *(uint4*)&moeTr[li]     = *(const uint4*)gp;
        *(uint4*)&moeTr[li + 8] = *(const uint4*)(gp + 8);
      } else {
        uint4 z = {0,0,0,0};
        *(uint4*)&moeTr[li] = z; *(uint4*)&moeTr[li + 8] = z;
      }
    }
  }
  if (t < 512) {
    int a = t >> 5, s = 200 + (t & 31);
    wgtT[a*WGSTR + s] = 0;
  }

  if (t < A_) { counts[t] = 0; maxpos[t] = -1; }
  float wv = -3.0e38f;
  if (t < S_) {
    int s = t;
    padl[s] = (iseq[base+s] == 0) ? 1 : 0;
    idxl[s] = (int)idxf[base+s];
    wv = w_in[base+s];
    #pragma unroll
    for (int q = 0; q < 4; ++q)
      *(float4*)&bij[s*20 + 4*q] = *(const float4*)&graw[(base+s)*A_ + 4*q];
  }
  __syncthreads();

  // ---- hoist step2 A-fragments: moeTr is loop-invariant ----
  short8 a2[7];
  {
    unsigned vA = (unsigned)(w*7168 + lane*8);
    #pragma unroll
    for (int ks = 0; ks < 7; ++ks) {
      long long r0, r1;
      asm volatile(
        "ds_read_b64_tr_b16 %0, %2\n\t"
        "ds_read_b64_tr_b16 %1, %2 offset:512\n\t"
        "s_waitcnt lgkmcnt(0)"
        : "=&v"(r0), "=&v"(r1) : "v"(vA + (unsigned)(ks*1024)) : "memory");
      __builtin_amdgcn_sched_barrier(0);
      union { short8 v; long long q[2]; } uu;
      uu.q[0] = r0; uu.q[1] = r1;
      a2[ks] = uu.v;
    }
  }

  if (t < S_ && !padl[t]) {
    atomicAdd(&counts[idxl[t]], 1);
    atomicMax(&maxpos[idxl[t]], t + 1);
  }
  float mxw = blk_max(wv, red);
  float ev = (t < S_) ? expf(wv - mxw) : 0.f;
  float sw = blk_sum(ev, red);
  if (t < S_) tmaL[t] = ev / sw;
  __syncthreads();
  if (t < A_) {
    int c = counts[t];
    float mkv = (c == 0) ? 1.f : 0.f;
    maskf[t] = mkv;
    mask_out[b*A_ + t] = mkv;
    int mp = maxpos[t];
    aidx_out[b*A_ + t] = (mp > 0) ? (float)(mp - 1) : -1.f;
  }
  __syncthreads();

  for (int iter = 0; iter < 3; ++iter) {
    // ---- step1: wave-parallel masked softmax over a, scaled by tma ----
    #pragma unroll
    for (int pass = 0; pass < 4; ++pass) {
      int s = pass*64 + (t >> 4);
      int a = t & 15;
      if (s < S_) {
        float v = bij[s*20 + a];
        v = (maskf[a] > 0.5f) ? NEGV : v;
        float mx = v;
        #pragma unroll
        for (int mk = 1; mk < 16; mk <<= 1) mx = fmaxf(mx, __shfl_xor(mx, mk));
        float e = expf(v - mx);
        float sm = e;
        #pragma unroll
        for (int mk = 1; mk < 16; mk <<= 1) sm += __shfl_xor(sm, mk);
        float sc = (padl[s] ? 0.f : tmaL[s]) / sm;
        wgtT[a*WGSTR + s] = bf16u(e*sc);
      }
    }
    __syncthreads();

    // ---- step2: 7 MFMA, A from registers ----
    f32x4 acc = (f32x4){0.f,0.f,0.f,0.f};
    #pragma unroll
    for (int ks = 0; ks < 7; ++ks) {
      short8 bf = *(const short8*)&wgtT[la*WGSTR + ks*32 + lg*8];
      acc = __builtin_amdgcn_mfma_f32_16x16x32_bf16(a2[ks], bf, acc, 0, 0, 0);
    }
    // ---- step3: squash ----
    {
      float n2 = acc[0]*acc[0] + acc[1]*acc[1] + acc[2]*acc[2] + acc[3]*acc[3];
      n2 += __shfl_xor(n2, 16);
      n2 += __shfl_xor(n2, 32);
      if (lane < 16) n2p[w*17 + lane] = n2;
    }
    __syncthreads();
    if (t < 16) {
      float sv = 0.f;
      #pragma unroll
      for (int w2 = 0; w2 < 16; ++w2) sv += n2p[w2*17 + t];
      n2s[t] = sv / (1.f + sv) / sqrtf(sv + 1e-9f);
    }
    __syncthreads();
    {
      float sc = n2s[la];
      if (iter < 2) {
        #pragma unroll
        for (int r = 0; r < 4; ++r)
          capB[la*CBSTR + w*16 + lg*4 + r] = bf16u(acc[r]*sc);
      } else {
        float* capl = bij;
        #pragma unroll
        for (int r = 0; r < 4; ++r)
          capl[la*CLSTR + w*16 + lg*4 + r] = acc[r]*sc;
      }
    }
    __syncthreads();

    // ---- step4: bij += moe . cap ----
    if (iter < 2) {
      if (w < 13) {
        int sR = w*16 + la;
        int ksS = sR >> 5, s4l = (sR >> 2) & 7, sr = sR & 3;
        int bp = (s4l & 1) ? 4 + (s4l >> 1) : (s4l >> 1);
        int laneA = ksS*512 + bp*64 + sr*16 + (lg & 1)*8 + (lg >> 1)*3584;
        f32x4 accS = (f32x4){0.f,0.f,0.f,0.f};
        #pragma unroll
        for (int k4 = 0; k4 < 8; ++k4) {
          short8 am = *(const short8*)&moeTr[laneA + k4*7168];
          short8 bc = *(const short8*)&capB[la*CBSTR + k4*32 + lg*8];
          accS = __builtin_amdgcn_mfma_f32_16x16x32_bf16(am, bc, accS, 0, 0, 0);
        }
        int sW = w*16 + lg*4;
        #pragma unroll
        for (int r = 0; r < 4; ++r)
          if (sW + r < S_) bij[(sW + r)*20 + la] += accS[r];
      }
      __syncthreads();
    }
  }

  // final cap write
  {
    const float* capl = bij;
    int a = t >> 6, h4 = t & 63;
    float4 v = *(const float4*)&capl[a*CLSTR + 4*h4];
    *(float4*)&cap_out[((size_t)b*A_ + a)*H_ + 4*h4] = v;
  }
}

// ---------------- gather: activated[b,s,:] = cap[b, idx[b,s], :] ----------------
__global__ __launch_bounds__(256) void gather_kernel(
    const float* __restrict__ capv, const float* __restrict__ idxf,
    float* __restrict__ act)
{
  int e4 = blockIdx.x * 256 + threadIdx.x;   // 819200 float4s
  int m = e4 >> 6, h4 = e4 & 63;
  int b = m / S_;
  int id = (int)idxf[m];
  float4 v = *(const float4*)&capv[((b*A_) + id)*H_ + 4*h4];
  *(float4*)&act[(size_t)4*e4] = v;
}

extern "C" void kernel_launch(void* const* d_in, const int* in_sizes, int n_in,
                              void* d_out, int out_size, void* d_ws, size_t ws_size,
                              hipStream_t stream) {
  (void)in_sizes; (void)n_in; (void)out_size; (void)ws_size;
  const float* item  = (const float*)d_in[0];
  const int*   iseq  = (const int*)d_in[1];
  const int*   tseq  = (const int*)d_in[2];
  const float* W_lin = (const float*)d_in[3];
  const float* b_lin = (const float*)d_in[4];
  const float* asp   = (const float*)d_in[5];
  const float* pos   = (const float*)d_in[6];
  const float* tdt   = (const float*)d_in[7];
  const float* tdn   = (const float*)d_in[8];
  const float* Wa1   = (const float*)d_in[9];
  const float* ba1   = (const float*)d_in[10];
  const float* Wa2   = (const float*)d_in[11];
  const float* ba2   = (const float*)d_in[12];
  const float* g_ln  = (const float*)d_in[13];
  const float* b_ln  = (const float*)d_in[14];

  float* out    = (float*)d_out;
  float* cap_o  = out;                 // B*A*H     = 262144
  float* gate_o = out + 262144;        // B*S*A     = 204800
  float* mask_o = out + 466944;        // B*A       = 1024
  float* act_o  = out + 467968;        // B*S*H     = 3276800
  float* aidx_o = out + 3744768;       // B*A       = 1024
  float* idx_o  = out + 3745792;       // B*S       = 12800

  // ws: moeB bf16 (6.55MB) | Wa1T | WlinT | w f32 | graw f32
  ushortT* moeB  = (ushortT*)d_ws;
  ushortT* Wa1T  = (ushortT*)((char*)d_ws + 6553600);
  ushortT* WlinT = (ushortT*)((char*)d_ws + 6553600 + 131072);
  float*   w_ws  = (float*)((char*)d_ws + 6553600 + 262144);
  float*   graw  = (float*)((char*)d_ws + 6553600 + 262144 + 51200);

  prepT_kernel<<<32, 256, 0, stream>>>(Wa1, W_lin, Wa1T, WlinT);
  gemmx_kernel<<<600, 512, 0, stream>>>(item, iseq, tseq, pos, tdt, tdn, asp,
      Wa1T, WlinT, ba1, Wa2, ba2, b_lin, g_ln, b_ln, w_ws, moeB,
      graw, gate_o, idx_o);
  phaseC_kernel<<<B_, 1024, 0, stream>>>(iseq, w_ws, moeB, idx_o, graw,
      cap_o, mask_o, aidx_o);
  gather_kernel<<<(M_*H_/4)/256, 256, 0, stream>>>(cap_o, idx_o, act_o);
}

// Round 8
// 57.724 us; speedup vs baseline: 1.0451x; 1.0451x over previous
//
#include <hip/hip_runtime.h>

#define B_ 64
#define S_ 200
#define H_ 256
#define A_ 16
#define M_ (B_*S_)
#define NEGV (-1000000000.0f)

typedef unsigned short ushortT;
typedef __attribute__((ext_vector_type(8))) short short8;
typedef __attribute__((ext_vector_type(4))) float f32x4;

__device__ __forceinline__ ushortT bf16u(float f) {
  unsigned int u = __builtin_bit_cast(unsigned int, f);
  unsigned int r = (u + 0x7fffu + ((u >> 16) & 1u)) >> 16;
  return (ushortT)r;
}
__device__ __forceinline__ float bf2f(ushortT u) {
  unsigned int v = ((unsigned int)u) << 16;
  return __builtin_bit_cast(float, v);
}

// ---------------- prepT: weight transposes only (32 blocks) ----------------
__global__ __launch_bounds__(256) void prepT_kernel(
    const float* __restrict__ Wa1, const float* __restrict__ W_lin,
    ushortT* __restrict__ Wa1T, ushortT* __restrict__ WlinT)
{
  __shared__ float T[64*65];
  const int blk = blockIdx.x, t = threadIdx.x;
  int wsel = blk >> 4;
  int tile = blk & 15;
  const float* W = wsel ? W_lin : Wa1;
  ushortT* WT = wsel ? WlinT : Wa1T;
  int tr = (tile >> 2) * 64, tc = (tile & 3) * 64;
  #pragma unroll
  for (int p = 0; p < 16; ++p) {
    int r = p*4 + (t >> 6);
    int c = t & 63;
    T[c*65 + r] = W[(tr + r)*H_ + tc + c];
  }
  __syncthreads();
  #pragma unroll
  for (int p = 0; p < 16; ++p) {
    int n = p*4 + (t >> 6);
    int k = t & 63;
    WT[(tc + n)*H_ + tr + k] = bf16u(T[n*65 + k]);
  }
}

// ---------------- fused front: 200 blocks x 512 thr, single scheduling round ----------------
// Dual GEMM (A sliced dbuf + B dbuf, 1 barrier/k-step) + w/moe epilogues + gates/idx.
// LDS carve (u16 idx): Atma bufs [2][64][40] @0, Aitm @5120, B0 [2][256][40] @10240, B1 @30720.
// After k-loop the whole region is dead -> aspl (f32[16][260]) and gL (f32[64][20]) alias it.
__global__ __launch_bounds__(512) void fused_kernel(
    const float* __restrict__ item, const int* __restrict__ iseq,
    const int* __restrict__ tseq, const float* __restrict__ pos,
    const float* __restrict__ tdt, const float* __restrict__ tdn,
    const float* __restrict__ asp,
    const ushortT* __restrict__ Wa1T, const ushortT* __restrict__ WlinT,
    const float* __restrict__ ba1, const float* __restrict__ Wa2,
    const float* __restrict__ ba2, const float* __restrict__ b_lin,
    const float* __restrict__ g_ln, const float* __restrict__ b_ln,
    float* __restrict__ w_out, ushortT* __restrict__ moe_outB,
    float* __restrict__ graw, float* __restrict__ gates_sm,
    float* __restrict__ idxf)
{
  __shared__ __align__(16) ushortT smem[51200];   // 102,400 B
  __shared__ int sL[64], ttL[64], tnL[64];
  __shared__ float wp[2][64], ln1[2][64], ln2[2][64], mus[64], rss[64];

  const int t = threadIdx.x;
  const int m0 = blockIdx.x * 64;
  const int lane = t & 63, w = t >> 6;
  const int g = w >> 2, wl = w & 3;
  const int wm = wl >> 1, wn = wl & 1;
  const int col = lane & 15;
  const int rg  = lane >> 4;

  if (t < 64) {
    int m = m0 + t;
    sL[t]  = m % S_;
    ttL[t] = tseq[2*m];
    tnL[t] = tseq[2*m+1];
  }
  __syncthreads();

  const int arow = t >> 3;          // 0..63
  const int ac4  = (t & 7) * 4;     // 0..28
  const int nr   = t >> 1;          // 0..255
  const int kh   = (t & 1) * 16;
  const int srow = sL[arow], trow = ttL[arow], nrow = tnL[arow];

  ushortT* const Atma0 = smem;            // + p*2560
  ushortT* const Aitm0 = smem + 5120;     // + p*2560
  ushortT* const B0b   = smem + 10240;    // + p*10240
  ushortT* const B1b   = smem + 30720;    // + p*10240

  // prefetch + stage k-step 0 into buf 0
  float4 pi = *(const float4*)&item[(size_t)(m0+arow)*H_ + ac4];
  float4 pp = *(const float4*)&pos[srow*H_ + ac4];
  float4 pt = *(const float4*)&tdt[trow*H_ + ac4];
  float4 pn = *(const float4*)&tdn[nrow*H_ + ac4];
  uint4 b0a = *(const uint4*)&Wa1T[(size_t)nr*H_ + kh];
  uint4 b0b = *(const uint4*)&Wa1T[(size_t)nr*H_ + kh + 8];
  uint4 b1a = *(const uint4*)&WlinT[(size_t)nr*H_ + kh];
  uint4 b1b = *(const uint4*)&WlinT[(size_t)nr*H_ + kh + 8];
  {
    union { ushortT u[4]; uint2 v; } ci, ct;
    ci.u[0] = bf16u(pi.x); ci.u[1] = bf16u(pi.y);
    ci.u[2] = bf16u(pi.z); ci.u[3] = bf16u(pi.w);
    ct.u[0] = bf16u(pi.x + pp.x + pt.x + pn.x);
    ct.u[1] = bf16u(pi.y + pp.y + pt.y + pn.y);
    ct.u[2] = bf16u(pi.z + pp.z + pt.z + pn.z);
    ct.u[3] = bf16u(pi.w + pp.w + pt.w + pn.w);
    *(uint2*)&Aitm0[arow*40 + ac4] = ci.v;
    *(uint2*)&Atma0[arow*40 + ac4] = ct.v;
    *(uint4*)&B0b[nr*40 + kh]     = b0a;
    *(uint4*)&B0b[nr*40 + kh + 8] = b0b;
    *(uint4*)&B1b[nr*40 + kh]     = b1a;
    *(uint4*)&B1b[nr*40 + kh + 8] = b1b;
  }
  __syncthreads();

  f32x4 acc[2][8];
  #pragma unroll
  for (int r = 0; r < 2; ++r)
    #pragma unroll
    for (int q = 0; q < 8; ++q) acc[r][q] = (f32x4){0.f,0.f,0.f,0.f};

  #pragma unroll
  for (int ks = 0; ks < 8; ++ks) {
    if (ks < 7) {
      const int k1 = (ks + 1) * 32;
      pi = *(const float4*)&item[(size_t)(m0+arow)*H_ + k1 + ac4];
      pp = *(const float4*)&pos[srow*H_ + k1 + ac4];
      pt = *(const float4*)&tdt[trow*H_ + k1 + ac4];
      pn = *(const float4*)&tdn[nrow*H_ + k1 + ac4];
      b0a = *(const uint4*)&Wa1T[(size_t)nr*H_ + k1 + kh];
      b0b = *(const uint4*)&Wa1T[(size_t)nr*H_ + k1 + kh + 8];
      b1a = *(const uint4*)&WlinT[(size_t)nr*H_ + k1 + kh];
      b1b = *(const uint4*)&WlinT[(size_t)nr*H_ + k1 + kh + 8];
    }
    // compute k-step ks from buf p
    {
      const int p = ks & 1;
      const ushortT* Ab = (g ? Aitm0 : Atma0) + p*2560;
      const ushortT* Bb = (g ? B1b : B0b) + p*10240;
      short8 af0 = *(const short8*)&Ab[(wm*32 + col)*40 + rg*8];
      short8 af1 = *(const short8*)&Ab[(wm*32 + 16 + col)*40 + rg*8];
      #pragma unroll
      for (int q = 0; q < 8; ++q) {
        short8 bf = *(const short8*)&Bb[(wn*128 + q*16 + col)*40 + rg*8];
        acc[0][q] = __builtin_amdgcn_mfma_f32_16x16x32_bf16(af0, bf, acc[0][q], 0, 0, 0);
        acc[1][q] = __builtin_amdgcn_mfma_f32_16x16x32_bf16(af1, bf, acc[1][q], 0, 0, 0);
      }
    }
    // stage k-step ks+1 into buf p^1 (that buf's readers finished at ks-1's barrier)
    if (ks < 7) {
      const int p = (ks + 1) & 1;
      union { ushortT u[4]; uint2 v; } ci, ct;
      ci.u[0] = bf16u(pi.x); ci.u[1] = bf16u(pi.y);
      ci.u[2] = bf16u(pi.z); ci.u[3] = bf16u(pi.w);
      ct.u[0] = bf16u(pi.x + pp.x + pt.x + pn.x);
      ct.u[1] = bf16u(pi.y + pp.y + pt.y + pn.y);
      ct.u[2] = bf16u(pi.z + pp.z + pt.z + pn.z);
      ct.u[3] = bf16u(pi.w + pp.w + pt.w + pn.w);
      *(uint2*)&(Aitm0 + p*2560)[arow*40 + ac4] = ci.v;
      *(uint2*)&(Atma0 + p*2560)[arow*40 + ac4] = ct.v;
      ushortT* B0w = B0b + p*10240;
      ushortT* B1w = B1b + p*10240;
      *(uint4*)&B0w[nr*40 + kh]     = b0a;
      *(uint4*)&B0w[nr*40 + kh + 8] = b0b;
      *(uint4*)&B1w[nr*40 + kh]     = b1a;
      *(uint4*)&B1w[nr*40 + kh + 8] = b1b;
    }
    __syncthreads();
  }

  // ---- stage aspect embeddings into (now dead) A/B region ----
  float* aspl = (float*)smem;            // [16][260] f32
  float* gL   = (float*)smem + 4160;     // [64][20]  f32
  #pragma unroll
  for (int i = 0; i < 2; ++i) {
    int e = t + 512*i;                   // 1024 float4
    int r = e >> 6, c = e & 63;
    *(float4*)&aspl[r*260 + 4*c] = *(const float4*)&asp[r*H_ + 4*c];
  }

  // ---- epilogue partials ----
  float glv[8], bbv[8];
  if (g == 0) {
    float bav[8], wav[8];
    #pragma unroll
    for (int q = 0; q < 8; ++q) {
      int n = wn*128 + q*16 + col;
      bav[q] = ba1[n]; wav[q] = Wa2[n];
    }
    #pragma unroll
    for (int r = 0; r < 2; ++r)
      #pragma unroll
      for (int j = 0; j < 4; ++j) {
        float p = 0.f;
        #pragma unroll
        for (int q = 0; q < 8; ++q) {
          float h = acc[r][q][j] + bav[q];
          h = (h >= 0.f) ? h : 0.01f*h;
          p += h * wav[q];
        }
        #pragma unroll
        for (int mk = 1; mk < 16; mk <<= 1) p += __shfl_xor(p, mk);
        if (col == 0) wp[wn][wm*32 + r*16 + rg*4 + j] = p;
      }
  } else {
    float blv[8];
    #pragma unroll
    for (int q = 0; q < 8; ++q) {
      int n = wn*128 + q*16 + col;
      blv[q] = b_lin[n]; glv[q] = g_ln[n]; bbv[q] = b_ln[n];
    }
    #pragma unroll
    for (int r = 0; r < 2; ++r)
      #pragma unroll
      for (int j = 0; j < 4; ++j) {
        int row = wm*32 + r*16 + rg*4 + j;
        float s1 = 0.f, s2 = 0.f;
        #pragma unroll
        for (int q = 0; q < 8; ++q) {
          int n = wn*128 + q*16 + col;
          float vv = tanhf(acc[r][q][j] + blv[q]) + item[(size_t)(m0+row)*H_ + n];
          acc[r][q][j] = vv; s1 += vv; s2 += vv*vv;
        }
        #pragma unroll
        for (int mk = 1; mk < 16; mk <<= 1) {
          s1 += __shfl_xor(s1, mk);
          s2 += __shfl_xor(s2, mk);
        }
        if (col == 0) { ln1[wn][row] = s1; ln2[wn][row] = s2; }
      }
  }
  __syncthreads();
  if (t < 64) {
    int row = t, m = m0 + row;
    w_out[m] = (iseq[m] == 0) ? NEGV : (wp[0][row] + wp[1][row] + ba2[0]);
  } else if (t < 128) {
    int row = t - 64;
    float s1 = ln1[0][row] + ln1[1][row];
    float s2 = ln2[0][row] + ln2[1][row];
    float mu  = s1 * (1.0f/H_);
    float var = s2 * (1.0f/H_) - mu*mu;
    mus[row] = mu;
    rss[row] = 1.0f / sqrtf(fmaxf(var, 0.f) + 1e-12f);
  }
  __syncthreads();
  if (g == 1) {
    #pragma unroll
    for (int r = 0; r < 2; ++r)
      #pragma unroll
      for (int j = 0; j < 4; ++j) {
        int row = wm*32 + r*16 + rg*4 + j;
        int m = m0 + row;
        float mu = mus[row], rs = rss[row];
        #pragma unroll
        for (int q = 0; q < 8; ++q) {
          int n = wn*128 + q*16 + col;
          moe_outB[(size_t)m*H_ + n] = bf16u((acc[r][q][j] - mu)*rs*glv[q] + bbv[q]);
        }
      }
  }

  // ---- gates for this block's 64 rows (f32, same summation order as before) ----
  {
    const int r8 = t >> 3, a2 = (t & 7) * 2;
    const int m = m0 + r8;
    float ga = 0.f, gb = 0.f;
    #pragma unroll 8
    for (int k4 = 0; k4 < 64; ++k4) {
      float4 xv = *(const float4*)&item[(size_t)m*H_ + 4*k4];
      float4 a0 = *(const float4*)&aspl[a2*260 + 4*k4];
      float4 a1 = *(const float4*)&aspl[(a2+1)*260 + 4*k4];
      ga += xv.x*a0.x + xv.y*a0.y + xv.z*a0.z + xv.w*a0.w;
      gb += xv.x*a1.x + xv.y*a1.y + xv.z*a1.z + xv.w*a1.w;
    }
    gL[r8*20 + a2]     = ga;
    gL[r8*20 + a2 + 1] = gb;
  }
  __syncthreads();
  if (t < 64) {
    float row[16];
    #pragma unroll
    for (int a = 0; a < 16; ++a) row[a] = gL[t*20 + a];
    float best = row[0]; int bi = 0;
    #pragma unroll
    for (int a = 1; a < 16; ++a)
      if (row[a] > best) { best = row[a]; bi = a; }
    idxf[m0 + t] = (float)bi;
    float mx = row[0];
    #pragma unroll
    for (int a = 1; a < 16; ++a) mx = fmaxf(mx, row[a]);
    float ex[16], sm = 0.f;
    #pragma unroll
    for (int a = 0; a < 16; ++a) { ex[a] = expf(row[a] - mx); sm += ex[a]; }
    float inv = 1.f / sm;
    #pragma unroll
    for (int q = 0; q < 4; ++q) {
      float4 rv; rv.x = row[4*q]; rv.y = row[4*q+1]; rv.z = row[4*q+2]; rv.w = row[4*q+3];
      *(float4*)&graw[(m0+t)*A_ + 4*q] = rv;
      float4 o; o.x = ex[4*q]*inv; o.y = ex[4*q+1]*inv; o.z = ex[4*q+2]*inv; o.w = ex[4*q+3]*inv;
      *(float4*)&gates_sm[(m0+t)*A_ + 4*q] = o;
    }
  }
}

// ---------------- Phase C: MFMA routing + activated write (one block per batch) ----------------
__device__ __forceinline__ float blk_max(float v, float* red) {
  #pragma unroll
  for (int mk = 32; mk; mk >>= 1) v = fmaxf(v, __shfl_xor(v, mk));
  int t = threadIdx.x;
  if ((t & 63) == 0) red[t >> 6] = v;
  __syncthreads();
  if (t < 64) {
    float x = (t < 16) ? red[t] : -3.0e38f;
    #pragma unroll
    for (int mk = 8; mk; mk >>= 1) x = fmaxf(x, __shfl_xor(x, mk));
    if (t == 0) red[0] = x;
  }
  __syncthreads();
  float r = red[0];
  __syncthreads();
  return r;
}

__device__ __forceinline__ float blk_sum(float v, float* red) {
  #pragma unroll
  for (int mk = 32; mk; mk >>= 1) v += __shfl_xor(v, mk);
  int t = threadIdx.x;
  if ((t & 63) == 0) red[t >> 6] = v;
  __syncthreads();
  if (t < 64) {
    float x = (t < 16) ? red[t] : 0.f;
    #pragma unroll
    for (int mk = 8; mk; mk >>= 1) x += __shfl_xor(x, mk);
    if (t == 0) red[0] = x;
  }
  __syncthreads();
  float r = red[0];
  __syncthreads();
  return r;
}

// moeTr layout: [ht=16][ks=7][bp=8][sr=4][hc=16] bf16 (see r4 notes).
#define WGSTR 232
#define CBSTR 260
#define CLSTR 252

__global__ __launch_bounds__(1024) void phaseC_kernel(
    const int* __restrict__ iseq, const float* __restrict__ w_in,
    const ushortT* __restrict__ moeB, const float* __restrict__ idxf,
    const float* __restrict__ graw,
    float* __restrict__ cap_out,    // OUT0
    float* __restrict__ mask_out,   // OUT2
    float* __restrict__ aidx_out,   // OUT4
    float* __restrict__ act_out)    // OUT3 (activated)
{
  __shared__ ushortT moeTr[57344];
  __shared__ ushortT wgtT[16*WGSTR];
  __shared__ ushortT capB[16*CBSTR];
  __shared__ float bij[4032];
  __shared__ float n2p[16*17];
  __shared__ float n2s[16];
  __shared__ float tmaL[S_];
  __shared__ float red[16];
  __shared__ float maskf[A_];
  __shared__ int counts[A_], maxpos[A_];
  __shared__ int idxl[S_];
  __shared__ int padl[S_];

  const int t = threadIdx.x;
  const int b = blockIdx.x;
  const int base = b * S_;
  const int lane = t & 63, w = t >> 6;
  const int la = lane & 15, lg = lane >> 4;

  #pragma unroll
  for (int u = 0; u < 4; ++u) {
    int e = t + 1024*u;
    if (e < 3584) {
      int ht = e & 15, s = e >> 4;
      int ks = s >> 5, s4l = (s >> 2) & 7, sr = s & 3;
      int bp = (s4l & 1) ? 4 + (s4l >> 1) : (s4l >> 1);
      int li = ((ht*7 + ks)*8 + bp)*64 + sr*16;
      if (s < S_) {
        const ushortT* gp = &moeB[((size_t)(base + s))*H_ + ht*16];
        *(uint4*)&moeTr[li]     = *(const uint4*)gp;
        *(uint4*)&moeTr[li + 8] = *(const uint4*)(gp + 8);
      } else {
        uint4 z = {0,0,0,0};
        *(uint4*)&moeTr[li] = z; *(uint4*)&moeTr[li + 8] = z;
      }
    }
  }
  if (t < 512) {
    int a = t >> 5, s = 200 + (t & 31);
    wgtT[a*WGSTR + s] = 0;
  }

  if (t < A_) { counts[t] = 0; maxpos[t] = -1; }
  float wv = -3.0e38f;
  if (t < S_) {
    int s = t;
    padl[s] = (iseq[base+s] == 0) ? 1 : 0;
    idxl[s] = (int)idxf[base+s];
    wv = w_in[base+s];
    #pragma unroll
    for (int q = 0; q < 4; ++q)
      *(float4*)&bij[s*20 + 4*q] = *(const float4*)&graw[(base+s)*A_ + 4*q];
  }
  __syncthreads();

  // hoist step2 A-fragments (moeTr loop-invariant)
  short8 a2[7];
  {
    unsigned vA = (unsigned)(w*7168 + lane*8);
    #pragma unroll
    for (int ks = 0; ks < 7; ++ks) {
      long long r0, r1;
      asm volatile(
        "ds_read_b64_tr_b16 %0, %2\n\t"
        "ds_read_b64_tr_b16 %1, %2 offset:512\n\t"
        "s_waitcnt lgkmcnt(0)"
        : "=&v"(r0), "=&v"(r1) : "v"(vA + (unsigned)(ks*1024)) : "memory");
      __builtin_amdgcn_sched_barrier(0);
      union { short8 v; long long q[2]; } uu;
      uu.q[0] = r0; uu.q[1] = r1;
      a2[ks] = uu.v;
    }
  }

  if (t < S_ && !padl[t]) {
    atomicAdd(&counts[idxl[t]], 1);
    atomicMax(&maxpos[idxl[t]], t + 1);
  }
  float mxw = blk_max(wv, red);
  float ev = (t < S_) ? expf(wv - mxw) : 0.f;
  float sw = blk_sum(ev, red);
  if (t < S_) tmaL[t] = ev / sw;
  __syncthreads();
  if (t < A_) {
    int c = counts[t];
    float mkv = (c == 0) ? 1.f : 0.f;
    maskf[t] = mkv;
    mask_out[b*A_ + t] = mkv;
    int mp = maxpos[t];
    aidx_out[b*A_ + t] = (mp > 0) ? (float)(mp - 1) : -1.f;
  }
  __syncthreads();

  for (int iter = 0; iter < 3; ++iter) {
    // step1: wave-parallel masked softmax over a, scaled by tma
    #pragma unroll
    for (int pass = 0; pass < 4; ++pass) {
      int s = pass*64 + (t >> 4);
      int a = t & 15;
      if (s < S_) {
        float v = bij[s*20 + a];
        v = (maskf[a] > 0.5f) ? NEGV : v;
        float mx = v;
        #pragma unroll
        for (int mk = 1; mk < 16; mk <<= 1) mx = fmaxf(mx, __shfl_xor(mx, mk));
        float e = expf(v - mx);
        float sm = e;
        #pragma unroll
        for (int mk = 1; mk < 16; mk <<= 1) sm += __shfl_xor(sm, mk);
        float sc = (padl[s] ? 0.f : tmaL[s]) / sm;
        wgtT[a*WGSTR + s] = bf16u(e*sc);
      }
    }
    __syncthreads();

    // step2: 7 MFMA, A from registers
    f32x4 acc = (f32x4){0.f,0.f,0.f,0.f};
    #pragma unroll
    for (int ks = 0; ks < 7; ++ks) {
      short8 bf = *(const short8*)&wgtT[la*WGSTR + ks*32 + lg*8];
      acc = __builtin_amdgcn_mfma_f32_16x16x32_bf16(a2[ks], bf, acc, 0, 0, 0);
    }
    // step3: squash
    {
      float n2 = acc[0]*acc[0] + acc[1]*acc[1] + acc[2]*acc[2] + acc[3]*acc[3];
      n2 += __shfl_xor(n2, 16);
      n2 += __shfl_xor(n2, 32);
      if (lane < 16) n2p[w*17 + lane] = n2;
    }
    __syncthreads();
    if (t < 16) {
      float sv = 0.f;
      #pragma unroll
      for (int w2 = 0; w2 < 16; ++w2) sv += n2p[w2*17 + t];
      n2s[t] = sv / (1.f + sv) / sqrtf(sv + 1e-9f);
    }
    __syncthreads();
    {
      float sc = n2s[la];
      if (iter < 2) {
        #pragma unroll
        for (int r = 0; r < 4; ++r)
          capB[la*CBSTR + w*16 + lg*4 + r] = bf16u(acc[r]*sc);
      } else {
        float* capl = bij;
        #pragma unroll
        for (int r = 0; r < 4; ++r)
          capl[la*CLSTR + w*16 + lg*4 + r] = acc[r]*sc;
      }
    }
    __syncthreads();

    // step4: bij += moe . cap
    if (iter < 2) {
      if (w < 13) {
        int sR = w*16 + la;
        int ksS = sR >> 5, s4l = (sR >> 2) & 7, sr = sR & 3;
        int bp = (s4l & 1) ? 4 + (s4l >> 1) : (s4l >> 1);
        int laneA = ksS*512 + bp*64 + sr*16 + (lg & 1)*8 + (lg >> 1)*3584;
        f32x4 accS = (f32x4){0.f,0.f,0.f,0.f};
        #pragma unroll
        for (int k4 = 0; k4 < 8; ++k4) {
          short8 am = *(const short8*)&moeTr[laneA + k4*7168];
          short8 bc = *(const short8*)&capB[la*CBSTR + k4*32 + lg*8];
          accS = __builtin_amdgcn_mfma_f32_16x16x32_bf16(am, bc, accS, 0, 0, 0);
        }
        int sW = w*16 + lg*4;
        #pragma unroll
        for (int r = 0; r < 4; ++r)
          if (sW + r < S_) bij[(sW + r)*20 + la] += accS[r];
      }
      __syncthreads();
    }
  }

  // final cap + activated writes
  {
    const float* capl = bij;
    int a = t >> 6, h4 = t & 63;
    float4 v = *(const float4*)&capl[a*CLSTR + 4*h4];
    *(float4*)&cap_out[((size_t)b*A_ + a)*H_ + 4*h4] = v;
    for (int s = t >> 6; s < S_; s += 16) {
      float4 av = *(const float4*)&capl[idxl[s]*CLSTR + 4*h4];
      *(float4*)&act_out[((size_t)base + s)*H_ + 4*h4] = av;
    }
  }
}

extern "C" void kernel_launch(void* const* d_in, const int* in_sizes, int n_in,
                              void* d_out, int out_size, void* d_ws, size_t ws_size,
                              hipStream_t stream) {
  (void)in_sizes; (void)n_in; (void)out_size; (void)ws_size;
  const float* item  = (const float*)d_in[0];
  const int*   iseq  = (const int*)d_in[1];
  const int*   tseq  = (const int*)d_in[2];
  const float* W_lin = (const float*)d_in[3];
  const float* b_lin = (const float*)d_in[4];
  const float* asp   = (const float*)d_in[5];
  const float* pos   = (const float*)d_in[6];
  const float* tdt   = (const float*)d_in[7];
  const float* tdn   = (const float*)d_in[8];
  const float* Wa1   = (const float*)d_in[9];
  const float* ba1   = (const float*)d_in[10];
  const float* Wa2   = (const float*)d_in[11];
  const float* ba2   = (const float*)d_in[12];
  const float* g_ln  = (const float*)d_in[13];
  const float* b_ln  = (const float*)d_in[14];

  float* out    = (float*)d_out;
  float* cap_o  = out;                 // B*A*H     = 262144
  float* gate_o = out + 262144;        // B*S*A     = 204800
  float* mask_o = out + 466944;        // B*A       = 1024
  float* act_o  = out + 467968;        // B*S*H     = 3276800
  float* aidx_o = out + 3744768;       // B*A       = 1024
  float* idx_o  = out + 3745792;       // B*S       = 12800

  // ws: moeB bf16 (6.55MB) | Wa1T | WlinT | w f32 | graw f32
  ushortT* moeB  = (ushortT*)d_ws;
  ushortT* Wa1T  = (ushortT*)((char*)d_ws + 6553600);
  ushortT* WlinT = (ushortT*)((char*)d_ws + 6553600 + 131072);
  float*   w_ws  = (float*)((char*)d_ws + 6553600 + 262144);
  float*   graw  = (float*)((char*)d_ws + 6553600 + 262144 + 51200);

  prepT_kernel<<<32, 256, 0, stream>>>(Wa1, W_lin, Wa1T, WlinT);
  fused_kernel<<<200, 512, 0, stream>>>(item, iseq, tseq, pos, tdt, tdn, asp,
      Wa1T, WlinT, ba1, Wa2, ba2, b_lin, g_ln, b_ln, w_ws, moeB,
      graw, gate_o, idx_o);
  phaseC_kernel<<<B_, 1024, 0, stream>>>(iseq, w_ws, moeB, idx_o, graw,
      cap_o, mask_o, aidx_o, act_o);
}